// Round 8
// baseline (1878.014 us; speedup 1.0000x reference)
//
#include <hip/hip_runtime.h>
#include <cstdint>

#define H_DIM 512
#define B_DIM 256
#define T_DIM 256

typedef __bf16 bf16x8 __attribute__((ext_vector_type(8)));
typedef __bf16 bf16x4 __attribute__((ext_vector_type(4)));
typedef float  f32x4  __attribute__((ext_vector_type(4)));
typedef unsigned long long ull;

__device__ __forceinline__ void cvt_split(float4 a, float4 b, bf16x8& h, bf16x8& lo) {
  const float v[8] = {a.x, a.y, a.z, a.w, b.x, b.y, b.z, b.w};
#pragma unroll
  for (int j = 0; j < 8; ++j) {
    h[j]  = (__bf16)v[j];
    lo[j] = (__bf16)(v[j] - (float)h[j]);
  }
}

__device__ __forceinline__ bf16x8 cvt8(const float* p) {
  const float4 s0 = *(const float4*)p;
  const float4 s1 = *(const float4*)(p + 4);
  bf16x8 v;
  v[0] = (__bf16)s0.x; v[1] = (__bf16)s0.y; v[2] = (__bf16)s0.z; v[3] = (__bf16)s0.w;
  v[4] = (__bf16)s1.x; v[5] = (__bf16)s1.y; v[6] = (__bf16)s1.z; v[7] = (__bf16)s1.w;
  return v;
}

// =====================================================================
// K1: Ux[(t*256+b)*512 + i] = sum_k x[b][t][k]*U[i][k] + bias[i]
// bf16 split-MFMA (xh@Uh + xh@Ul + xl@Uh ~ f32 accurate), f32 output.
// =====================================================================
__global__ __launch_bounds__(256, 2) void k1_ux(const float* __restrict__ x,
                                                const float* __restrict__ U,
                                                const float* __restrict__ bias,
                                                float* __restrict__ Ux) {
  __shared__ __align__(16) __bf16 XH[128][40];
  __shared__ __align__(16) __bf16 XL[128][40];
  __shared__ __align__(16) __bf16 UH[128][40];
  __shared__ __align__(16) __bf16 UL[128][40];

  const int tid = threadIdx.x;
  const int l   = tid & 63;
  const int w   = tid >> 6;
  const int wm  = w >> 1;
  const int wn  = w & 1;
  const int r0  = blockIdx.x * 128;
  const int i0  = blockIdx.y * 128;
  const int t   = r0 >> 8;
  const int b0  = r0 & 255;

  const int srow  = tid >> 1;
  const int shalf = tid & 1;

  f32x4 acc[4][4];
#pragma unroll
  for (int mi = 0; mi < 4; ++mi)
#pragma unroll
    for (int ni = 0; ni < 4; ++ni) acc[mi][ni] = (f32x4){0.f, 0.f, 0.f, 0.f};

  const int lrow = l & 15;
  const int lgrn = (l >> 4) * 8;

  for (int k0 = 0; k0 < H_DIM; k0 += 32) {
    __syncthreads();
    {
      const float* xsrc = x + ((size_t)(b0 + srow) * T_DIM + t) * H_DIM + k0 + shalf * 16;
      const float* usrc = U + (size_t)(i0 + srow) * H_DIM + k0 + shalf * 16;
      bf16x8 h0, l0, h1, l1;
      cvt_split(*(const float4*)xsrc, *(const float4*)(xsrc + 4), h0, l0);
      cvt_split(*(const float4*)(xsrc + 8), *(const float4*)(xsrc + 12), h1, l1);
      *(bf16x8*)&XH[srow][shalf * 16]     = h0;
      *(bf16x8*)&XH[srow][shalf * 16 + 8] = h1;
      *(bf16x8*)&XL[srow][shalf * 16]     = l0;
      *(bf16x8*)&XL[srow][shalf * 16 + 8] = l1;
      cvt_split(*(const float4*)usrc, *(const float4*)(usrc + 4), h0, l0);
      cvt_split(*(const float4*)(usrc + 8), *(const float4*)(usrc + 12), h1, l1);
      *(bf16x8*)&UH[srow][shalf * 16]     = h0;
      *(bf16x8*)&UH[srow][shalf * 16 + 8] = h1;
      *(bf16x8*)&UL[srow][shalf * 16]     = l0;
      *(bf16x8*)&UL[srow][shalf * 16 + 8] = l1;
    }
    __syncthreads();

    bf16x8 ah[4], al[4], bh[4], blo[4];
#pragma unroll
    for (int mi = 0; mi < 4; ++mi) {
      ah[mi] = *(const bf16x8*)&XH[wm * 64 + mi * 16 + lrow][lgrn];
      al[mi] = *(const bf16x8*)&XL[wm * 64 + mi * 16 + lrow][lgrn];
    }
#pragma unroll
    for (int ni = 0; ni < 4; ++ni) {
      bh[ni]  = *(const bf16x8*)&UH[wn * 64 + ni * 16 + lrow][lgrn];
      blo[ni] = *(const bf16x8*)&UL[wn * 64 + ni * 16 + lrow][lgrn];
    }
#pragma unroll
    for (int mi = 0; mi < 4; ++mi)
#pragma unroll
      for (int ni = 0; ni < 4; ++ni) {
        acc[mi][ni] = __builtin_amdgcn_mfma_f32_16x16x32_bf16(ah[mi], bh[ni],  acc[mi][ni], 0, 0, 0);
        acc[mi][ni] = __builtin_amdgcn_mfma_f32_16x16x32_bf16(ah[mi], blo[ni], acc[mi][ni], 0, 0, 0);
        acc[mi][ni] = __builtin_amdgcn_mfma_f32_16x16x32_bf16(al[mi], bh[ni],  acc[mi][ni], 0, 0, 0);
      }
  }

  float bv[4];
#pragma unroll
  for (int ni = 0; ni < 4; ++ni) bv[ni] = bias[i0 + wn * 64 + ni * 16 + lrow];
#pragma unroll
  for (int mi = 0; mi < 4; ++mi)
#pragma unroll
    for (int ni = 0; ni < 4; ++ni) {
      const int col = i0 + wn * 64 + ni * 16 + lrow;
      const int row = r0 + wm * 64 + mi * 16 + (l >> 4) * 4;
#pragma unroll
      for (int r = 0; r < 4; ++r)
        Ux[(size_t)(row + r) * H_DIM + col] = acc[mi][ni][r] + bv[ni];
    }
}

// =====================================================================
// K2: scan. 64 blocks x 512 threads. bid = slice*8 + g.
//   Swapped-operand MFMA: C'[f][b] = [W;A] . y^T (see R7 notes).
//   W/A operand frags now live in LDS in FRAG ORDER (staged once):
//     wave fq's section at fq*32768; W frag ks at ks*1024 + l*16,
//     A frags at +16384. Per-step: 32 x ds_read_b128 (wave-local,
//     identity store/read mapping -> no barrier needed after init).
//   ybuf tile layout & sync protocol unchanged from R7.
//   Epilogue transcendentals via v_exp_f32 (__expf) + v_rcp.
// =====================================================================
__global__ __launch_bounds__(512, 1) void k2_scan(const float* __restrict__ W,
                                                  const float* __restrict__ Amat,
                                                  const float* __restrict__ y0,
                                                  const float* __restrict__ Ux,
                                                  const float* __restrict__ Wro,
                                                  __bf16* __restrict__ ybuf,      // 2 x 131072 bf16 (tile order)
                                                  float* __restrict__ plog,       // [T][32][B]
                                                  unsigned int* __restrict__ flags) {  // [8][2][32]
  extern __shared__ __align__(16) char smem[];   // 128 KiB operand frags

  const int tid   = threadIdx.x;
  const int g     = blockIdx.x & 7;
  const int slice = blockIdx.x >> 3;
  const int fbase = slice * 64;

  const int l   = tid & 63;
  const int w   = tid >> 6;      // 0..7
  const int bh  = w & 1;         // batch half (16)
  const int fq  = w >> 1;        // feature 16-group within 64-slice
  const int l15 = l & 15;
  const int lhi = l >> 4;        // 0..3

  const int b_loc  = bh * 16 + l15;             // epilogue batch (C col) & frag row
  const int b_glob = g * 32 + b_loc;
  const int f0     = fbase + fq * 16 + lhi * 4; // lane's 4 output features (C rows)
  const int frow   = fbase + fq * 16 + l15;     // lane's W/A frag row (operand A)

  // ---- own f32 state: y[b_glob][f0..f0+3] ----
  float4 yst4 = *(const float4*)(y0 + (size_t)b_glob * H_DIM + f0);
  float yst[4] = {yst4.x, yst4.y, yst4.z, yst4.w};
  const float4 wrov = *(const float4*)(Wro + f0);

  // ---- stage W/A operand frags into LDS (frag order, once) ----
  char* ldsW = smem + (size_t)fq * 32768;
  char* ldsA = ldsW + 16384;
#pragma unroll
  for (int ks = 0; ks < 16; ++ks) {
    *(bf16x8*)(ldsW + ks * 1024 + l * 16) = cvt8(W    + (size_t)frow * H_DIM + ks * 32 + lhi * 8);
    *(bf16x8*)(ldsA + ks * 1024 + l * 16) = cvt8(Amat + (size_t)frow * H_DIM + ks * 32 + lhi * 8);
  }
  __syncthreads();

  // ---- store addressing (from f0, within own (g,bh) tile) ----
  const size_t tix  = (size_t)(g * 2 + bh);
  const int ks_s = f0 >> 5;
  const int m_s  = (f0 >> 3) & 3;
  const int jh_s = (f0 >> 2) & 1;
  const size_t st_off = tix * 16384 + (size_t)ks_s * 1024 + (size_t)jh_s * 512
                      + (size_t)(m_s * 16 + l15) * 8;

  for (int t = 0; t < T_DIM; ++t) {
    // input-path term: issue before the wait (latency hides under it)
    const float4 uxv = *(const float4*)(Ux + ((size_t)t * B_DIM + b_glob) * H_DIM + f0);

    // ---- wait: the 32 waves of (g, bh) published y_t ----
    if (t > 0) {
      const unsigned target = (unsigned)t;
      const unsigned int* fp = flags + g * 64 + bh * 32 + l;
      for (;;) {
        unsigned v = target;
        if (l < 32)
          v = __hip_atomic_load(fp, __ATOMIC_RELAXED, __HIP_MEMORY_SCOPE_AGENT);
        if (__all(v >= target)) break;
        __builtin_amdgcn_s_sleep(1);
      }
      asm volatile("" ::: "memory");
    }

    // ---- y operand-B frags: 2 coalesced 8B loads per ks ----
    bf16x8 bv[16];
    if (t == 0) {
      const float* pa = y0 + (size_t)(g * 32 + bh * 16 + l15) * H_DIM + lhi * 8;
#pragma unroll
      for (int ks = 0; ks < 16; ++ks) bv[ks] = cvt8(pa + ks * 32);
    } else {
      const char* abase = (const char*)ybuf + (size_t)(t & 1) * 262144
                        + tix * 16384 + (size_t)l * 8;
#pragma unroll
      for (int ks = 0; ks < 16; ++ks) {
        ull u2[2];
        u2[0] = __hip_atomic_load((const ull*)(abase + ks * 1024),
                                  __ATOMIC_RELAXED, __HIP_MEMORY_SCOPE_AGENT);
        u2[1] = __hip_atomic_load((const ull*)(abase + ks * 1024 + 512),
                                  __ATOMIC_RELAXED, __HIP_MEMORY_SCOPE_AGENT);
        __builtin_memcpy(&bv[ks], u2, 16);
      }
    }

    // ---- MFMA: operands from LDS (ds_read_b128), K=512, 2-way chains ----
    f32x4 accP0 = {0.f, 0.f, 0.f, 0.f}, accP1 = {0.f, 0.f, 0.f, 0.f};
    f32x4 accG0 = {0.f, 0.f, 0.f, 0.f}, accG1 = {0.f, 0.f, 0.f, 0.f};
#pragma unroll
    for (int ks = 0; ks < 16; ks += 2) {
      const bf16x8 w0 = *(const bf16x8*)(ldsW + ks * 1024 + l * 16);
      const bf16x8 a0 = *(const bf16x8*)(ldsA + ks * 1024 + l * 16);
      const bf16x8 w1 = *(const bf16x8*)(ldsW + (ks + 1) * 1024 + l * 16);
      const bf16x8 a1 = *(const bf16x8*)(ldsA + (ks + 1) * 1024 + l * 16);
      accP0 = __builtin_amdgcn_mfma_f32_16x16x32_bf16(w0, bv[ks],     accP0, 0, 0, 0);
      accG0 = __builtin_amdgcn_mfma_f32_16x16x32_bf16(a0, bv[ks],     accG0, 0, 0, 0);
      accP1 = __builtin_amdgcn_mfma_f32_16x16x32_bf16(w1, bv[ks + 1], accP1, 0, 0, 0);
      accG1 = __builtin_amdgcn_mfma_f32_16x16x32_bf16(a1, bv[ks + 1], accG1, 0, 0, 0);
    }

    // ---- register epilogue: 4 features x 1 batch per lane ----
    float s = 0.0f;
    bf16x4 pk;
    const float uxa[4] = {uxv.x, uxv.y, uxv.z, uxv.w};
    const float wra[4] = {wrov.x, wrov.y, wrov.z, wrov.w};
#pragma unroll
    for (int r = 0; r < 4; ++r) {
      const float pre  = accP0[r] + accP1[r] + uxa[r];
      // tanh(pre) = 1 - 2/(e^{2 pre} + 1)   (inf-safe: e2=inf -> 1; e2=0 -> -1)
      const float e2   = __expf(2.0f * pre);
      const float th   = 1.0f - 2.0f * __builtin_amdgcn_rcpf(e2 + 1.0f);
      // sigmoid(gv) = 1/(1 + e^{-gv})
      const float eg   = __expf(-(accG0[r] + accG1[r]));
      const float gate = __builtin_amdgcn_rcpf(1.0f + eg);
      const float yn   = yst[r] + 0.1f * th * gate;
      yst[r] = yn;
      pk[r] = (__bf16)yn;
      s += yn * wra[r];
    }
    ull pv;
    __builtin_memcpy(&pv, &pk, 8);
    ull* dst = (ull*)((char*)ybuf + (size_t)((t + 1) & 1) * 262144 + st_off);
    __hip_atomic_store(dst, pv, __ATOMIC_RELAXED, __HIP_MEMORY_SCOPE_AGENT);

    // readout partial: reduce over the 4 lhi feature-groups
    s += __shfl_xor(s, 16, 64);
    s += __shfl_xor(s, 32, 64);
    if (l < 16)
      plog[((size_t)t * 32 + slice * 4 + fq) * B_DIM + g * 32 + bh * 16 + l] = s;

    // ---- per-wave release: drain own stores, publish wave flag ----
    asm volatile("s_waitcnt vmcnt(0)" ::: "memory");
    if (l == 0)
      __hip_atomic_store(flags + g * 64 + bh * 32 + slice * 4 + fq, (unsigned)(t + 1),
                         __ATOMIC_RELAXED, __HIP_MEMORY_SCOPE_AGENT);
  }
}

// =====================================================================
// K3: out[b][t] = bro + sum_{c<32} plog[t][c][b]
// =====================================================================
__global__ __launch_bounds__(256) void k3_out(const float* __restrict__ plog,
                                              const float* __restrict__ bro,
                                              float* __restrict__ out) {
  const int t = blockIdx.x;
  const int b = threadIdx.x;
  float s = bro[0];
#pragma unroll
  for (int col = 0; col < 32; ++col)
    s += plog[((size_t)t * 32 + col) * B_DIM + b];
  out[(size_t)b * T_DIM + t] = s;
}

// =====================================================================
extern "C" void kernel_launch(void* const* d_in, const int* in_sizes, int n_in,
                              void* d_out, int out_size, void* d_ws, size_t ws_size,
                              hipStream_t stream) {
  const float* x   = (const float*)d_in[0];
  const float* y0  = (const float*)d_in[1];
  const float* W   = (const float*)d_in[2];
  const float* U   = (const float*)d_in[3];
  const float* b   = (const float*)d_in[4];
  const float* A   = (const float*)d_in[5];
  const float* Wro = (const float*)d_in[6];
  const float* bro = (const float*)d_in[7];
  float* out = (float*)d_out;

  float* ws = (float*)d_ws;
  float* Ux = ws;                                               // 33,554,432 f32
  __bf16* ybuf = (__bf16*)(ws + (size_t)T_DIM * B_DIM * H_DIM); // 262,144 bf16 (tile order)
  float* plog = ws + (size_t)T_DIM * B_DIM * H_DIM + 131072;    // 2,097,152 f32
  unsigned int* flags = (unsigned int*)(plog + (size_t)T_DIM * 32 * B_DIM);  // 512 u32

  (void)in_sizes; (void)n_in; (void)out_size; (void)ws_size;

  hipFuncSetAttribute(reinterpret_cast<const void*>(k2_scan),
                      hipFuncAttributeMaxDynamicSharedMemorySize, 131072);
  hipMemsetAsync(flags, 0, 512 * sizeof(unsigned int), stream);

  dim3 g1(512, 4);
  k1_ux<<<g1, 256, 0, stream>>>(x, U, b, Ux);
  k2_scan<<<64, 512, 131072, stream>>>(W, A, y0, Ux, Wro, ybuf, plog, flags);
  k3_out<<<256, 256, 0, stream>>>(plog, bro, out);
}

// Round 10
// 1431.469 us; speedup vs baseline: 1.3119x; 1.3119x over previous
//
#include <hip/hip_runtime.h>
#include <cstdint>

#define H_DIM 512
#define B_DIM 256
#define T_DIM 256

typedef __bf16 bf16x8 __attribute__((ext_vector_type(8)));
typedef __bf16 bf16x4 __attribute__((ext_vector_type(4)));
typedef float  f32x4  __attribute__((ext_vector_type(4)));
typedef unsigned long long ull;

__device__ __forceinline__ void cvt_split(float4 a, float4 b, bf16x8& h, bf16x8& lo) {
  const float v[8] = {a.x, a.y, a.z, a.w, b.x, b.y, b.z, b.w};
#pragma unroll
  for (int j = 0; j < 8; ++j) {
    h[j]  = (__bf16)v[j];
    lo[j] = (__bf16)(v[j] - (float)v[j] + (float)(v[j] - (float)h[j]));  // folded below
  }
#pragma unroll
  for (int j = 0; j < 8; ++j) {
    h[j]  = (__bf16)v[j];
    lo[j] = (__bf16)(v[j] - (float)h[j]);
  }
}

// =====================================================================
// K1: Ux[(t*256+b)*512 + i] = sum_k x[b][t][k]*U[i][k] + bias[i]
// bf16 split-MFMA (xh@Uh + xh@Ul + xl@Uh ~ f32 accurate), f32 output.
// (R7-proven)
// =====================================================================
__global__ __launch_bounds__(256, 2) void k1_ux(const float* __restrict__ x,
                                                const float* __restrict__ U,
                                                const float* __restrict__ bias,
                                                float* __restrict__ Ux) {
  __shared__ __align__(16) __bf16 XH[128][40];
  __shared__ __align__(16) __bf16 XL[128][40];
  __shared__ __align__(16) __bf16 UH[128][40];
  __shared__ __align__(16) __bf16 UL[128][40];

  const int tid = threadIdx.x;
  const int l   = tid & 63;
  const int w   = tid >> 6;
  const int wm  = w >> 1;
  const int wn  = w & 1;
  const int r0  = blockIdx.x * 128;
  const int i0  = blockIdx.y * 128;
  const int t   = r0 >> 8;
  const int b0  = r0 & 255;

  const int srow  = tid >> 1;
  const int shalf = tid & 1;

  f32x4 acc[4][4];
#pragma unroll
  for (int mi = 0; mi < 4; ++mi)
#pragma unroll
    for (int ni = 0; ni < 4; ++ni) acc[mi][ni] = (f32x4){0.f, 0.f, 0.f, 0.f};

  const int lrow = l & 15;
  const int lgrn = (l >> 4) * 8;

  for (int k0 = 0; k0 < H_DIM; k0 += 32) {
    __syncthreads();
    {
      const float* xsrc = x + ((size_t)(b0 + srow) * T_DIM + t) * H_DIM + k0 + shalf * 16;
      const float* usrc = U + (size_t)(i0 + srow) * H_DIM + k0 + shalf * 16;
      bf16x8 h0, l0, h1, l1;
      cvt_split(*(const float4*)xsrc, *(const float4*)(xsrc + 4), h0, l0);
      cvt_split(*(const float4*)(xsrc + 8), *(const float4*)(xsrc + 12), h1, l1);
      *(bf16x8*)&XH[srow][shalf * 16]     = h0;
      *(bf16x8*)&XH[srow][shalf * 16 + 8] = h1;
      *(bf16x8*)&XL[srow][shalf * 16]     = l0;
      *(bf16x8*)&XL[srow][shalf * 16 + 8] = l1;
      cvt_split(*(const float4*)usrc, *(const float4*)(usrc + 4), h0, l0);
      cvt_split(*(const float4*)(usrc + 8), *(const float4*)(usrc + 12), h1, l1);
      *(bf16x8*)&UH[srow][shalf * 16]     = h0;
      *(bf16x8*)&UH[srow][shalf * 16 + 8] = h1;
      *(bf16x8*)&UL[srow][shalf * 16]     = l0;
      *(bf16x8*)&UL[srow][shalf * 16 + 8] = l1;
    }
    __syncthreads();

    bf16x8 ah[4], al[4], bh[4], blo[4];
#pragma unroll
    for (int mi = 0; mi < 4; ++mi) {
      ah[mi] = *(const bf16x8*)&XH[wm * 64 + mi * 16 + lrow][lgrn];
      al[mi] = *(const bf16x8*)&XL[wm * 64 + mi * 16 + lrow][lgrn];
    }
#pragma unroll
    for (int ni = 0; ni < 4; ++ni) {
      bh[ni]  = *(const bf16x8*)&UH[wn * 64 + ni * 16 + lrow][lgrn];
      blo[ni] = *(const bf16x8*)&UL[wn * 64 + ni * 16 + lrow][lgrn];
    }
#pragma unroll
    for (int mi = 0; mi < 4; ++mi)
#pragma unroll
      for (int ni = 0; ni < 4; ++ni) {
        acc[mi][ni] = __builtin_amdgcn_mfma_f32_16x16x32_bf16(ah[mi], bh[ni],  acc[mi][ni], 0, 0, 0);
        acc[mi][ni] = __builtin_amdgcn_mfma_f32_16x16x32_bf16(ah[mi], blo[ni], acc[mi][ni], 0, 0, 0);
        acc[mi][ni] = __builtin_amdgcn_mfma_f32_16x16x32_bf16(al[mi], bh[ni],  acc[mi][ni], 0, 0, 0);
      }
  }

  float bvv[4];
#pragma unroll
  for (int ni = 0; ni < 4; ++ni) bvv[ni] = bias[i0 + wn * 64 + ni * 16 + lrow];
#pragma unroll
  for (int mi = 0; mi < 4; ++mi)
#pragma unroll
    for (int ni = 0; ni < 4; ++ni) {
      const int col = i0 + wn * 64 + ni * 16 + lrow;
      const int row = r0 + wm * 64 + mi * 16 + (l >> 4) * 4;
#pragma unroll
      for (int r = 0; r < 4; ++r)
        Ux[(size_t)(row + r) * H_DIM + col] = acc[mi][ni][r] + bvv[ni];
    }
}

// =====================================================================
// K2: scan (R4 structure, proven 1140us, + proven micro-fixes).
//   64 blocks x 512 threads. bid = slice*8 + g.
//   group g = 32 batches; slice = 64 features.
//   Exchanged y via L3 with RELAXED agent atomics (no cache maintenance).
//   W/A fragments VGPR-resident (bfr[2][8] per wave, 64 VGPRs).
//   y_t staged to LDS (bf16, XOR-swizzled) once per step.
//   8 waves = (otype, ng, khalf); per wave 2Mx2Nx8K = 32 MFMA.
//   Own y state: 4 registers/thread (exact f32).
//   Changes vs R4: __expf epilogue (R7-proven); per-wave flag publish
//   (R7-proven); plog store after flag.
// =====================================================================
__device__ __forceinline__ unsigned swz(unsigned row, unsigned b) {
  return row * 1024u + (b ^ ((row & 7u) << 4));
}

__global__ __launch_bounds__(512, 1) void k2_scan(const float* __restrict__ W,
                                                  const float* __restrict__ Amat,
                                                  const float* __restrict__ y0,
                                                  const float* __restrict__ Ux,
                                                  const float* __restrict__ Wro,
                                                  __bf16* __restrict__ ybuf,      // 2*256*512 bf16
                                                  float* __restrict__ plog,       // [T][8][B]
                                                  unsigned int* __restrict__ flags) {  // [8][64]
  __shared__ __align__(16) char Ylds[32 * 1024];   // 32 rows x 512 bf16, swizzled
  __shared__ float Xex[2][2][32][68];              // [otype][khalf][b][f] padded
  const int tid   = threadIdx.x;
  const int g     = blockIdx.x & 7;
  const int slice = blockIdx.x >> 3;
  const int fbase = slice * 64;

  const int l     = tid & 63;
  const int w     = tid >> 6;        // 0..7
  const int otype = w >> 2;          // 0 = pre (W), 1 = gate (A)
  const int ng    = (w >> 1) & 1;    // feature 32-group within 64
  const int khalf = w & 1;           // K 256-split

  const int bl     = tid >> 4;       // batch 0..31
  const int f0i    = (tid & 15) * 4; // feature 0..60
  const int b_glob = g * 32 + bl;

  // ---- own y0 state -> registers ----
  float4 yst = *(const float4*)(y0 + (size_t)b_glob * H_DIM + fbase + f0i);
  const float4 wrov = *(const float4*)(Wro + fbase + f0i);

  // ---- W/A fragments -> VGPRs (once) ----
  const int n0    = l & 15;
  const int kfrag = khalf * 256 + ((l >> 4) * 8);
  const float* Bsrc = otype ? Amat : W;
  bf16x8 bfr[2][8];
#pragma unroll
  for (int ks = 0; ks < 8; ++ks) {
#pragma unroll
    for (int h2 = 0; h2 < 2; ++h2) {
      const float* src = Bsrc + (size_t)(fbase + ng * 32 + n0 + h2 * 16) * H_DIM + kfrag + ks * 32;
      const float4 s0 = *(const float4*)src;
      const float4 s1 = *(const float4*)(src + 4);
      bf16x8 v;
      v[0] = (__bf16)s0.x; v[1] = (__bf16)s0.y; v[2] = (__bf16)s0.z; v[3] = (__bf16)s0.w;
      v[4] = (__bf16)s1.x; v[5] = (__bf16)s1.y; v[6] = (__bf16)s1.z; v[7] = (__bf16)s1.w;
      bfr[h2][ks] = v;
    }
  }

  const unsigned ra0  = (unsigned)(l & 15);
  const unsigned ra1  = ra0 + 16u;
  const unsigned coff = (unsigned)((l >> 4) * 16 + khalf * 512);

  for (int t = 0; t < T_DIM; ++t) {
    // input-path term: issue before spin (latency hides under the wait)
    const float4 uxv = *(const float4*)(Ux + ((size_t)t * B_DIM + b_glob) * H_DIM + fbase + f0i);

    // ---- wait for all 64 waves of this group (relaxed coalesced polls) ----
    if (t > 0) {
      const unsigned target = (unsigned)t;
      const unsigned int* fp = flags + g * 64 + l;
      for (;;) {
        const unsigned v = __hip_atomic_load(fp, __ATOMIC_RELAXED, __HIP_MEMORY_SCOPE_AGENT);
        if (__all(v >= target)) break;
        __builtin_amdgcn_s_sleep(1);
      }
      asm volatile("" ::: "memory");
    }

    // ---- stage y_t -> Ylds (bf16, swizzled) ----
    if (t == 0) {
#pragma unroll
      for (int j = 0; j < 8; ++j) {
        const int chunk = j * 512 + tid;          // 4096 x 8B chunks
        const unsigned row = (unsigned)chunk >> 7;
        const unsigned b8  = ((unsigned)chunk & 127u) * 8u;
        const float4 s = *(const float4*)(y0 + (size_t)(g * 32 + row) * H_DIM + (chunk & 127) * 4);
        bf16x4 v;
        v[0] = (__bf16)s.x; v[1] = (__bf16)s.y; v[2] = (__bf16)s.z; v[3] = (__bf16)s.w;
        *(bf16x4*)(Ylds + swz(row, b8)) = v;
      }
    } else {
      const ull* src = (const ull*)(ybuf + (size_t)(t & 1) * (B_DIM * H_DIM)
                                    + (size_t)g * 32 * H_DIM);
#pragma unroll
      for (int j = 0; j < 8; ++j) {
        const int chunk = j * 512 + tid;
        const unsigned row = (unsigned)chunk >> 7;
        const unsigned b8  = ((unsigned)chunk & 127u) * 8u;
        const ull v = __hip_atomic_load(src + chunk, __ATOMIC_RELAXED, __HIP_MEMORY_SCOPE_AGENT);
        *(ull*)(Ylds + swz(row, b8)) = v;
      }
    }
    __syncthreads();

    // ---- MFMA: 2M x 2N x 8K per wave ----
    f32x4 acc00 = {0.f, 0.f, 0.f, 0.f};
    f32x4 acc01 = {0.f, 0.f, 0.f, 0.f};
    f32x4 acc10 = {0.f, 0.f, 0.f, 0.f};
    f32x4 acc11 = {0.f, 0.f, 0.f, 0.f};
#pragma unroll
    for (int ks = 0; ks < 8; ++ks) {
      const unsigned kb = coff + (unsigned)ks * 64u;
      const bf16x8 a0 = *(const bf16x8*)(Ylds + swz(ra0, kb));
      const bf16x8 a1 = *(const bf16x8*)(Ylds + swz(ra1, kb));
      acc00 = __builtin_amdgcn_mfma_f32_16x16x32_bf16(a0, bfr[0][ks], acc00, 0, 0, 0);
      acc01 = __builtin_amdgcn_mfma_f32_16x16x32_bf16(a0, bfr[1][ks], acc01, 0, 0, 0);
      acc10 = __builtin_amdgcn_mfma_f32_16x16x32_bf16(a1, bfr[0][ks], acc10, 0, 0, 0);
      acc11 = __builtin_amdgcn_mfma_f32_16x16x32_bf16(a1, bfr[1][ks], acc11, 0, 0, 0);
    }

    // ---- partial-tile exchange ----
    {
      const int lr = (l >> 4) * 4;
      const int lc = l & 15;
#pragma unroll
      for (int r = 0; r < 4; ++r) {
        Xex[otype][khalf][lr + r][ng * 32 + lc]           = acc00[r];
        Xex[otype][khalf][lr + r][ng * 32 + lc + 16]      = acc01[r];
        Xex[otype][khalf][lr + r + 16][ng * 32 + lc]      = acc10[r];
        Xex[otype][khalf][lr + r + 16][ng * 32 + lc + 16] = acc11[r];
      }
    }
    __syncthreads();

    // ---- epilogue: combine K-halves, state update, publish ----
    float s;
    {
      const float4 p0 = *(const float4*)&Xex[0][0][bl][f0i];
      const float4 p1 = *(const float4*)&Xex[0][1][bl][f0i];
      const float4 g0 = *(const float4*)&Xex[1][0][bl][f0i];
      const float4 g1 = *(const float4*)&Xex[1][1][bl][f0i];

      const float pr[4] = {p0.x + p1.x + uxv.x, p0.y + p1.y + uxv.y,
                           p0.z + p1.z + uxv.z, p0.w + p1.w + uxv.w};
      const float gv[4] = {g0.x + g1.x, g0.y + g1.y, g0.z + g1.z, g0.w + g1.w};
      const float yov[4] = {yst.x, yst.y, yst.z, yst.w};
      float yn[4];
#pragma unroll
      for (int j = 0; j < 4; ++j) {
        // tanh(pre) = 1 - 2/(e^{2 pre}+1); sigmoid(gv) = 1/(1+e^{-gv})
        const float e2   = __expf(2.0f * pr[j]);
        const float th   = 1.0f - 2.0f * __builtin_amdgcn_rcpf(e2 + 1.0f);
        const float eg   = __expf(-gv[j]);
        const float gate = __builtin_amdgcn_rcpf(1.0f + eg);
        yn[j] = yov[j] + 0.1f * th * gate;
      }
      yst.x = yn[0]; yst.y = yn[1]; yst.z = yn[2]; yst.w = yn[3];

      bf16x4 pk;
      pk[0] = (__bf16)yn[0]; pk[1] = (__bf16)yn[1];
      pk[2] = (__bf16)yn[2]; pk[3] = (__bf16)yn[3];
      ull pv;
      __builtin_memcpy(&pv, &pk, 8);
      ull* dst = (ull*)(ybuf + (size_t)((t + 1) & 1) * (B_DIM * H_DIM)
                        + (size_t)b_glob * H_DIM + fbase + f0i);
      __hip_atomic_store(dst, pv, __ATOMIC_RELAXED, __HIP_MEMORY_SCOPE_AGENT);

      s = yn[0] * wrov.x + yn[1] * wrov.y + yn[2] * wrov.z + yn[3] * wrov.w;
    }

    // ---- per-wave release: drain this wave's stores, publish wave flag ----
    asm volatile("s_waitcnt vmcnt(0)" ::: "memory");
    if (l == 0)
      __hip_atomic_store(flags + g * 64 + slice * 8 + w, (unsigned)(t + 1),
                         __ATOMIC_RELAXED, __HIP_MEMORY_SCOPE_AGENT);

    // readout partial (off critical path): reduce over the 16 feature-lanes
    s += __shfl_xor(s, 1, 64);
    s += __shfl_xor(s, 2, 64);
    s += __shfl_xor(s, 4, 64);
    s += __shfl_xor(s, 8, 64);
    if ((tid & 15) == 0)
      plog[((size_t)t * 8 + slice) * B_DIM + b_glob] = s;
  }
}

// =====================================================================
// K3: out[b][t] = bro + sum_{s<8} plog[t][s][b]
// =====================================================================
__global__ __launch_bounds__(256) void k3_out(const float* __restrict__ plog,
                                              const float* __restrict__ bro,
                                              float* __restrict__ out) {
  const int t = blockIdx.x;
  const int b = threadIdx.x;
  float s = bro[0];
#pragma unroll
  for (int col = 0; col < 8; ++col)
    s += plog[((size_t)t * 8 + col) * B_DIM + b];
  out[(size_t)b * T_DIM + t] = s;
}

// =====================================================================
extern "C" void kernel_launch(void* const* d_in, const int* in_sizes, int n_in,
                              void* d_out, int out_size, void* d_ws, size_t ws_size,
                              hipStream_t stream) {
  const float* x   = (const float*)d_in[0];
  const float* y0  = (const float*)d_in[1];
  const float* W   = (const float*)d_in[2];
  const float* U   = (const float*)d_in[3];
  const float* b   = (const float*)d_in[4];
  const float* A   = (const float*)d_in[5];
  const float* Wro = (const float*)d_in[6];
  const float* bro = (const float*)d_in[7];
  float* out = (float*)d_out;

  float* ws = (float*)d_ws;
  float* Ux = ws;                                               // 33,554,432 f32
  __bf16* ybuf = (__bf16*)(ws + (size_t)T_DIM * B_DIM * H_DIM); // 262,144 bf16
  float* plog = ws + (size_t)T_DIM * B_DIM * H_DIM + 131072;    // 524,288 f32
  unsigned int* flags = (unsigned int*)(plog + (size_t)T_DIM * 8 * B_DIM);  // 512 u32

  (void)in_sizes; (void)n_in; (void)out_size; (void)ws_size;

  hipMemsetAsync(flags, 0, 512 * sizeof(unsigned int), stream);

  dim3 g1(512, 4);
  k1_ux<<<g1, 256, 0, stream>>>(x, U, b, Ux);
  k2_scan<<<64, 512, 0, stream>>>(W, A, y0, Ux, Wro, ybuf, plog, flags);
  k3_out<<<256, 256, 0, stream>>>(plog, bro, out);
}

// Round 12
// 1038.347 us; speedup vs baseline: 1.8087x; 1.3786x over previous
//
#include <hip/hip_runtime.h>
#include <cstdint>
#include <cstring>

#define H_DIM 512
#define B_DIM 256
#define T_DIM 256

typedef __bf16 bf16x8 __attribute__((ext_vector_type(8)));
typedef __bf16 bf16x4 __attribute__((ext_vector_type(4)));
typedef float  f32x4  __attribute__((ext_vector_type(4)));
typedef unsigned long long ull;

__device__ __forceinline__ void cvt_split(float4 a, float4 b, bf16x8& h, bf16x8& lo) {
  const float v[8] = {a.x, a.y, a.z, a.w, b.x, b.y, b.z, b.w};
#pragma unroll
  for (int j = 0; j < 8; ++j) {
    h[j]  = (__bf16)v[j];
    lo[j] = (__bf16)(v[j] - (float)h[j]);
  }
}

__device__ __forceinline__ unsigned pack2bf(float a, float b) {
  const __bf16 ba = (__bf16)a, bb = (__bf16)b;
  unsigned short sa, sb;
  __builtin_memcpy(&sa, &ba, 2);
  __builtin_memcpy(&sb, &bb, 2);
  return (unsigned)sa | ((unsigned)sb << 16);
}

// =====================================================================
// K1: Ux[(t*256+b)*512 + i] = sum_k x[b][t][k]*U[i][k] + bias[i]
// bf16 split-MFMA (xh@Uh + xh@Ul + xl@Uh ~ f32 accurate), f32 output.
// (R7-proven)
// =====================================================================
__global__ __launch_bounds__(256, 2) void k1_ux(const float* __restrict__ x,
                                                const float* __restrict__ U,
                                                const float* __restrict__ bias,
                                                float* __restrict__ Ux) {
  __shared__ __align__(16) __bf16 XH[128][40];
  __shared__ __align__(16) __bf16 XL[128][40];
  __shared__ __align__(16) __bf16 UH[128][40];
  __shared__ __align__(16) __bf16 UL[128][40];

  const int tid = threadIdx.x;
  const int l   = tid & 63;
  const int w   = tid >> 6;
  const int wm  = w >> 1;
  const int wn  = w & 1;
  const int r0  = blockIdx.x * 128;
  const int i0  = blockIdx.y * 128;
  const int t   = r0 >> 8;
  const int b0  = r0 & 255;

  const int srow  = tid >> 1;
  const int shalf = tid & 1;

  f32x4 acc[4][4];
#pragma unroll
  for (int mi = 0; mi < 4; ++mi)
#pragma unroll
    for (int ni = 0; ni < 4; ++ni) acc[mi][ni] = (f32x4){0.f, 0.f, 0.f, 0.f};

  const int lrow = l & 15;
  const int lgrn = (l >> 4) * 8;

  for (int k0 = 0; k0 < H_DIM; k0 += 32) {
    __syncthreads();
    {
      const float* xsrc = x + ((size_t)(b0 + srow) * T_DIM + t) * H_DIM + k0 + shalf * 16;
      const float* usrc = U + (size_t)(i0 + srow) * H_DIM + k0 + shalf * 16;
      bf16x8 h0, l0, h1, l1;
      cvt_split(*(const float4*)xsrc, *(const float4*)(xsrc + 4), h0, l0);
      cvt_split(*(const float4*)(xsrc + 8), *(const float4*)(xsrc + 12), h1, l1);
      *(bf16x8*)&XH[srow][shalf * 16]     = h0;
      *(bf16x8*)&XH[srow][shalf * 16 + 8] = h1;
      *(bf16x8*)&XL[srow][shalf * 16]     = l0;
      *(bf16x8*)&XL[srow][shalf * 16 + 8] = l1;
      cvt_split(*(const float4*)usrc, *(const float4*)(usrc + 4), h0, l0);
      cvt_split(*(const float4*)(usrc + 8), *(const float4*)(usrc + 12), h1, l1);
      *(bf16x8*)&UH[srow][shalf * 16]     = h0;
      *(bf16x8*)&UH[srow][shalf * 16 + 8] = h1;
      *(bf16x8*)&UL[srow][shalf * 16]     = l0;
      *(bf16x8*)&UL[srow][shalf * 16 + 8] = l1;
    }
    __syncthreads();

    bf16x8 ah[4], al[4], bh[4], blo[4];
#pragma unroll
    for (int mi = 0; mi < 4; ++mi) {
      ah[mi] = *(const bf16x8*)&XH[wm * 64 + mi * 16 + lrow][lgrn];
      al[mi] = *(const bf16x8*)&XL[wm * 64 + mi * 16 + lrow][lgrn];
    }
#pragma unroll
    for (int ni = 0; ni < 4; ++ni) {
      bh[ni]  = *(const bf16x8*)&UH[wn * 64 + ni * 16 + lrow][lgrn];
      blo[ni] = *(const bf16x8*)&UL[wn * 64 + ni * 16 + lrow][lgrn];
    }
#pragma unroll
    for (int mi = 0; mi < 4; ++mi)
#pragma unroll
      for (int ni = 0; ni < 4; ++ni) {
        acc[mi][ni] = __builtin_amdgcn_mfma_f32_16x16x32_bf16(ah[mi], bh[ni],  acc[mi][ni], 0, 0, 0);
        acc[mi][ni] = __builtin_amdgcn_mfma_f32_16x16x32_bf16(ah[mi], blo[ni], acc[mi][ni], 0, 0, 0);
        acc[mi][ni] = __builtin_amdgcn_mfma_f32_16x16x32_bf16(al[mi], bh[ni],  acc[mi][ni], 0, 0, 0);
      }
  }

  float bvv[4];
#pragma unroll
  for (int ni = 0; ni < 4; ++ni) bvv[ni] = bias[i0 + wn * 64 + ni * 16 + lrow];
#pragma unroll
  for (int mi = 0; mi < 4; ++mi)
#pragma unroll
    for (int ni = 0; ni < 4; ++ni) {
      const int col = i0 + wn * 64 + ni * 16 + lrow;
      const int row = r0 + wm * 64 + mi * 16 + (l >> 4) * 4;
#pragma unroll
      for (int r = 0; r < 4; ++r)
        Ux[(size_t)(row + r) * H_DIM + col] = acc[mi][ni][r] + bvv[ni];
    }
}

// =====================================================================
// K2: scan (R4 compute structure + fused data/seq packet sync).
//   64 blocks x 512 threads. bid = slice*8 + g.
//   Exchange: pkt[buf][g][row<32][fp<256] : u64 = [seq:32 | 2 x bf16].
//   Producer (step t): 2 x 8B relaxed-atomic stores at fp = slice*32 +
//   (tid&15)*2 (R11 BUG: slice*32 was missing -> fp>=32 never written ->
//   permanent spin). Consumer: load own 16 packets, validate hi32==t,
//   retry (__all) -> the poll IS the data load. Then swizzled LDS, barrier,
//   MFMA 2Mx2Nx8K/wave, Xex exchange, epilogue (expf).
//   WAR-safe: overwriting buf[t&1] (seq t+2, step t+1) requires validating
//   ALL seq=t+1 packets, which exist only after every block passed its
//   step-t staging barrier. Replay-safe: pkt memset to 0 per launch.
// =====================================================================
__device__ __forceinline__ unsigned swz(unsigned row, unsigned b) {
  return row * 1024u + (b ^ ((row & 7u) << 4));
}

__global__ __launch_bounds__(512, 1) void k2_scan(const float* __restrict__ W,
                                                  const float* __restrict__ Amat,
                                                  const float* __restrict__ y0,
                                                  const float* __restrict__ Ux,
                                                  const float* __restrict__ Wro,
                                                  ull* __restrict__ pkt,          // 2 x 65536 u64
                                                  float* __restrict__ plog) {     // [T][8][B]
  __shared__ __align__(16) char Ylds[32 * 1024];   // 32 rows x 512 bf16, swizzled
  __shared__ float Xex[2][2][32][68];              // [otype][khalf][b][f] padded
  const int tid   = threadIdx.x;
  const int g     = blockIdx.x & 7;
  const int slice = blockIdx.x >> 3;
  const int fbase = slice * 64;

  const int l     = tid & 63;
  const int w     = tid >> 6;        // 0..7
  const int otype = w >> 2;          // 0 = pre (W), 1 = gate (A)
  const int ng    = (w >> 1) & 1;    // feature 32-group within 64
  const int khalf = w & 1;           // K 256-split

  const int bl     = tid >> 4;       // batch 0..31
  const int f0i    = (tid & 15) * 4; // feature 0..60 (within 64-slice)
  const int b_glob = g * 32 + bl;

  // ---- own y0 state -> registers ----
  float4 yst = *(const float4*)(y0 + (size_t)b_glob * H_DIM + fbase + f0i);
  const float4 wrov = *(const float4*)(Wro + fbase + f0i);

  // ---- W/A fragments -> VGPRs (once) ----
  const int n0    = l & 15;
  const int kfrag = khalf * 256 + ((l >> 4) * 8);
  const float* Bsrc = otype ? Amat : W;
  bf16x8 bfr[2][8];
#pragma unroll
  for (int ks = 0; ks < 8; ++ks) {
#pragma unroll
    for (int h2 = 0; h2 < 2; ++h2) {
      const float* src = Bsrc + (size_t)(fbase + ng * 32 + n0 + h2 * 16) * H_DIM + kfrag + ks * 32;
      const float4 s0 = *(const float4*)src;
      const float4 s1 = *(const float4*)(src + 4);
      bf16x8 v;
      v[0] = (__bf16)s0.x; v[1] = (__bf16)s0.y; v[2] = (__bf16)s0.z; v[3] = (__bf16)s0.w;
      v[4] = (__bf16)s1.x; v[5] = (__bf16)s1.y; v[6] = (__bf16)s1.z; v[7] = (__bf16)s1.w;
      bfr[h2][ks] = v;
    }
  }

  const unsigned ra0  = (unsigned)(l & 15);
  const unsigned ra1  = ra0 + 16u;
  const unsigned coff = (unsigned)((l >> 4) * 16 + khalf * 512);

  // staging constants: this thread stages row = tid>>4, fp = (tid&15)+16j
  const unsigned srow = (unsigned)(tid >> 4);
  const unsigned scol = (unsigned)(tid & 15);
  // producer constants: global fp = (fbase + f0i)/2 = slice*32 + (tid&15)*2
  const size_t prod_base = (size_t)g * 8192 + (size_t)bl * 256
                         + (size_t)slice * 32 + (size_t)(tid & 15) * 2;

  for (int t = 0; t < T_DIM; ++t) {
    // input-path term: issue before the packet wait (latency hides under it)
    const float4 uxv = *(const float4*)(Ux + ((size_t)t * B_DIM + b_glob) * H_DIM + fbase + f0i);

    // ---- stage y_t -> Ylds ----
    if (t == 0) {
#pragma unroll
      for (int j = 0; j < 16; ++j) {
        const unsigned fp = scol + 16u * j;
        const float2 v = *(const float2*)(y0 + (size_t)(g * 32 + srow) * H_DIM + fp * 2);
        *(unsigned*)(Ylds + srow * 1024u + ((fp * 4u) ^ ((srow & 7u) << 4))) = pack2bf(v.x, v.y);
      }
    } else {
      // fused poll+load: packet hi32 must equal t
      const ull* src = pkt + (size_t)(t & 1) * 65536 + (size_t)g * 8192
                     + (size_t)srow * 256 + scol;
      ull pk[16];
      for (;;) {
        bool ok = true;
#pragma unroll
        for (int j = 0; j < 16; ++j) {
          pk[j] = __hip_atomic_load(src + (size_t)j * 16,
                                    __ATOMIC_RELAXED, __HIP_MEMORY_SCOPE_AGENT);
          ok &= ((unsigned)(pk[j] >> 32) == (unsigned)t);
        }
        if (__all(ok)) break;
        __builtin_amdgcn_s_sleep(1);
      }
#pragma unroll
      for (int j = 0; j < 16; ++j) {
        const unsigned fp = scol + 16u * j;
        *(unsigned*)(Ylds + srow * 1024u + ((fp * 4u) ^ ((srow & 7u) << 4))) = (unsigned)pk[j];
      }
    }
    __syncthreads();

    // ---- MFMA: 2M x 2N x 8K per wave ----
    f32x4 acc00 = {0.f, 0.f, 0.f, 0.f};
    f32x4 acc01 = {0.f, 0.f, 0.f, 0.f};
    f32x4 acc10 = {0.f, 0.f, 0.f, 0.f};
    f32x4 acc11 = {0.f, 0.f, 0.f, 0.f};
#pragma unroll
    for (int ks = 0; ks < 8; ++ks) {
      const unsigned kb = coff + (unsigned)ks * 64u;
      const bf16x8 a0 = *(const bf16x8*)(Ylds + swz(ra0, kb));
      const bf16x8 a1 = *(const bf16x8*)(Ylds + swz(ra1, kb));
      acc00 = __builtin_amdgcn_mfma_f32_16x16x32_bf16(a0, bfr[0][ks], acc00, 0, 0, 0);
      acc01 = __builtin_amdgcn_mfma_f32_16x16x32_bf16(a0, bfr[1][ks], acc01, 0, 0, 0);
      acc10 = __builtin_amdgcn_mfma_f32_16x16x32_bf16(a1, bfr[0][ks], acc10, 0, 0, 0);
      acc11 = __builtin_amdgcn_mfma_f32_16x16x32_bf16(a1, bfr[1][ks], acc11, 0, 0, 0);
    }

    // ---- partial-tile exchange ----
    {
      const int lr = (l >> 4) * 4;
      const int lc = l & 15;
#pragma unroll
      for (int r = 0; r < 4; ++r) {
        Xex[otype][khalf][lr + r][ng * 32 + lc]           = acc00[r];
        Xex[otype][khalf][lr + r][ng * 32 + lc + 16]      = acc01[r];
        Xex[otype][khalf][lr + r + 16][ng * 32 + lc]      = acc10[r];
        Xex[otype][khalf][lr + r + 16][ng * 32 + lc + 16] = acc11[r];
      }
    }
    __syncthreads();

    // ---- epilogue: combine K-halves, state update, publish packets ----
    float s;
    {
      const float4 p0 = *(const float4*)&Xex[0][0][bl][f0i];
      const float4 p1 = *(const float4*)&Xex[0][1][bl][f0i];
      const float4 g0 = *(const float4*)&Xex[1][0][bl][f0i];
      const float4 g1 = *(const float4*)&Xex[1][1][bl][f0i];

      const float pr[4] = {p0.x + p1.x + uxv.x, p0.y + p1.y + uxv.y,
                           p0.z + p1.z + uxv.z, p0.w + p1.w + uxv.w};
      const float gv[4] = {g0.x + g1.x, g0.y + g1.y, g0.z + g1.z, g0.w + g1.w};
      const float yov[4] = {yst.x, yst.y, yst.z, yst.w};
      float yn[4];
#pragma unroll
      for (int j = 0; j < 4; ++j) {
        // tanh(pre) = 1 - 2/(e^{2 pre}+1); sigmoid(gv) = 1/(1+e^{-gv})
        const float e2   = __expf(2.0f * pr[j]);
        const float th   = 1.0f - 2.0f * __builtin_amdgcn_rcpf(e2 + 1.0f);
        const float eg   = __expf(-gv[j]);
        const float gate = __builtin_amdgcn_rcpf(1.0f + eg);
        yn[j] = yov[j] + 0.1f * th * gate;
      }
      yst.x = yn[0]; yst.y = yn[1]; yst.z = yn[2]; yst.w = yn[3];

      // two self-validating 8B packets: [seq = t+1 | 2 x bf16]
      const ull seqw = ((ull)(unsigned)(t + 1)) << 32;
      ull* dst = pkt + (size_t)((t + 1) & 1) * 65536 + prod_base;
      __hip_atomic_store(dst,     seqw | pack2bf(yn[0], yn[1]),
                         __ATOMIC_RELAXED, __HIP_MEMORY_SCOPE_AGENT);
      __hip_atomic_store(dst + 1, seqw | pack2bf(yn[2], yn[3]),
                         __ATOMIC_RELAXED, __HIP_MEMORY_SCOPE_AGENT);

      s = yn[0] * wrov.x + yn[1] * wrov.y + yn[2] * wrov.z + yn[3] * wrov.w;
    }

    // readout partial (fire-and-forget): reduce over the 16 feature-lanes
    s += __shfl_xor(s, 1, 64);
    s += __shfl_xor(s, 2, 64);
    s += __shfl_xor(s, 4, 64);
    s += __shfl_xor(s, 8, 64);
    if ((tid & 15) == 0)
      plog[((size_t)t * 8 + slice) * B_DIM + b_glob] = s;
  }
}

// =====================================================================
// K3: out[b][t] = bro + sum_{s<8} plog[t][s][b]
// =====================================================================
__global__ __launch_bounds__(256) void k3_out(const float* __restrict__ plog,
                                              const float* __restrict__ bro,
                                              float* __restrict__ out) {
  const int t = blockIdx.x;
  const int b = threadIdx.x;
  float s = bro[0];
#pragma unroll
  for (int col = 0; col < 8; ++col)
    s += plog[((size_t)t * 8 + col) * B_DIM + b];
  out[(size_t)b * T_DIM + t] = s;
}

// =====================================================================
extern "C" void kernel_launch(void* const* d_in, const int* in_sizes, int n_in,
                              void* d_out, int out_size, void* d_ws, size_t ws_size,
                              hipStream_t stream) {
  const float* x   = (const float*)d_in[0];
  const float* y0  = (const float*)d_in[1];
  const float* W   = (const float*)d_in[2];
  const float* U   = (const float*)d_in[3];
  const float* b   = (const float*)d_in[4];
  const float* A   = (const float*)d_in[5];
  const float* Wro = (const float*)d_in[6];
  const float* bro = (const float*)d_in[7];
  float* out = (float*)d_out;

  float* ws = (float*)d_ws;
  float* Ux = ws;                                               // 33,554,432 f32
  ull* pkt = (ull*)(ws + (size_t)T_DIM * B_DIM * H_DIM);        // 2*65536 u64 (1 MB)
  float* plog = (float*)(pkt + 2 * 65536);                      // 524,288 f32

  (void)in_sizes; (void)n_in; (void)out_size; (void)ws_size;

  // MANDATORY: clear stale seq words from previous graph replays.
  hipMemsetAsync(pkt, 0, 2 * 65536 * sizeof(ull), stream);

  dim3 g1(512, 4);
  k1_ux<<<g1, 256, 0, stream>>>(x, U, b, Ux);
  k2_scan<<<64, 512, 0, stream>>>(W, A, y0, Ux, Wro, pkt, plog);
  k3_out<<<256, 256, 0, stream>>>(plog, bro, out);
}